// Round 7
// baseline (197.749 us; speedup 1.0000x reference)
//
#include <hip/hip_runtime.h>

// Problem constants
#define E   1024
#define SQ  2048
#define NR  4096    // N*S rows

typedef _Float16 half8  __attribute__((ext_vector_type(8)));
typedef _Float16 half4  __attribute__((ext_vector_type(4)));
typedef __fp16   fp16x2 __attribute__((ext_vector_type(2)));
typedef float    f32x4  __attribute__((ext_vector_type(4)));

#define MFMA_F16(a, b, c) __builtin_amdgcn_mfma_f32_16x16x32_f16((a), (b), (c), 0, 0, 0)

#if __has_builtin(__builtin_amdgcn_exp2f)
#define EXP2(x) __builtin_amdgcn_exp2f(x)
#else
#define EXP2(x) exp2f(x)
#endif

// Q pre-scale: (1/sqrt(E)) * log2(e) so softmax runs in exp2 domain
#define QSCALE 0.04508422002778011f

// async global->LDS, 16B per lane. LDS dest is wave-uniform base + lane*16.
__device__ __forceinline__ void async16(const void* g, void* l) {
  __builtin_amdgcn_global_load_lds((const __attribute__((address_space(1))) void*)g,
                                   (__attribute__((address_space(3))) void*)l, 16, 0, 0);
}

__device__ __forceinline__ float bperm_f(int srclane, float v) {
  return __int_as_float(__builtin_amdgcn_ds_bpermute(srclane << 2, __float_as_int(v)));
}

// -------- f32 -> f16 convert, all 5 tensors in one launch ------------------
__global__ __launch_bounds__(256)
void cvtall(const float* __restrict__ x, const float* __restrict__ wq,
            const float* __restrict__ wk, const float* __restrict__ wv,
            const float* __restrict__ wo,
            _Float16* __restrict__ xh, _Float16* __restrict__ wqh,
            _Float16* __restrict__ wkh, _Float16* __restrict__ wvh,
            _Float16* __restrict__ woh) {
  int b = blockIdx.x;
  const float* src; _Float16* dst; int off;
  if (b < 4096)      { src = x;  dst = xh;  off = b; }
  else if (b < 5120) { src = wq; dst = wqh; off = b - 4096; }
  else if (b < 6144) { src = wk; dst = wkh; off = b - 5120; }
  else if (b < 7168) { src = wv; dst = wvh; off = b - 6144; }
  else               { src = wo; dst = woh; off = b - 7168; }
  int i = off * 256 + threadIdx.x;
  f32x4 v = ((const f32x4*)src)[i];
  ((half4*)dst)[i] = __builtin_convertvector(v, half4);
}

// -------- QKV GEMM: C[M,N] = A[M,K] * B[N,K]^T, 128x128 tile, 2-phase dbuf -
// z=0: Q (scaled by QSCALE), z=1: K, z=2: V written transposed+permuted into
// Vg2[(n*16+h)*64 + d][s0 + c] where c = 32kk+8lg+4h'+jr <-> kv = 32kk+16h'+4lg+jr
// (the permutation the attn PV k-slot mapping expects).
__global__ __launch_bounds__(256, 2)
void gemm_qkv(const _Float16* __restrict__ A,
              const _Float16* __restrict__ B0, const _Float16* __restrict__ B1,
              const _Float16* __restrict__ B2,
              _Float16* __restrict__ C0, _Float16* __restrict__ C1,
              _Float16* __restrict__ Vg2,
              int M, int N, int K)
{
  const int z = blockIdx.z;
  const _Float16* B = (z == 0) ? B0 : ((z == 1) ? B1 : B2);
  __shared__ _Float16 As[2][128 * 64];
  __shared__ _Float16 Bs[2][128 * 64];
  const int tid = threadIdx.x;
  const int w = tid >> 6, lane = tid & 63;
  const int lr = lane & 15, lg = lane >> 4;
  const int l8 = lane >> 3, l7 = lane & 7;
  const int gch = l7 ^ (l8 & 7);
  const int tm = blockIdx.x * 128, tn = blockIdx.y * 128;
  const int wr = w >> 1, wc = w & 1;
  const int sl7 = lr & 7;

  // per-thread staging bases (advance by 64 elems per K-step)
  const _Float16* Ab = A + (size_t)(tm + w * 8 + l8) * K + gch * 8;
  const _Float16* Bb = B + (size_t)(tn + w * 8 + l8) * K + gch * 8;

  const f32x4 zv = {0.f, 0.f, 0.f, 0.f};
  f32x4 acc[4][4];
  #pragma unroll
  for (int mi = 0; mi < 4; mi++)
    #pragma unroll
    for (int ni = 0; ni < 4; ni++) acc[mi][ni] = zv;

  // prologue: stage ks=0 into buffer 0
  #pragma unroll
  for (int ci = 0; ci < 4; ci++) {
    async16(Ab + (size_t)(ci * 32) * K, (void*)(As[0] + (w + ci * 4) * 512));
    async16(Bb + (size_t)(ci * 32) * K, (void*)(Bs[0] + (w + ci * 4) * 512));
  }
  __syncthreads();

  int cur = 0;
  for (int ks = 0; ks < K; ks += 64) {
    if (ks + 64 < K) {    // issue next-tile staging before compute
      const _Float16* An = Ab + ks + 64;
      const _Float16* Bn = Bb + ks + 64;
      #pragma unroll
      for (int ci = 0; ci < 4; ci++) {
        async16(An + (size_t)(ci * 32) * K, (void*)(As[cur ^ 1] + (w + ci * 4) * 512));
        async16(Bn + (size_t)(ci * 32) * K, (void*)(Bs[cur ^ 1] + (w + ci * 4) * 512));
      }
    }
    #pragma unroll
    for (int kk = 0; kk < 2; kk++) {
      const int sl = ((kk * 4 + lg) ^ sl7) << 4;
      half8 af[4], bf[4];
      #pragma unroll
      for (int mi = 0; mi < 4; mi++)
        af[mi] = *(const half8*)((const char*)As[cur] + (wr * 64 + mi * 16 + lr) * 128 + sl);
      #pragma unroll
      for (int ni = 0; ni < 4; ni++)
        bf[ni] = *(const half8*)((const char*)Bs[cur] + (wc * 64 + ni * 16 + lr) * 128 + sl);
      #pragma unroll
      for (int mi = 0; mi < 4; mi++)
        #pragma unroll
        for (int ni = 0; ni < 4; ni++)
          acc[mi][ni] = MFMA_F16(af[mi], bf[ni], acc[mi][ni]);
    }
    __syncthreads();
    cur ^= 1;
  }
  if (z == 2) {
    // V permuted-transposed write, half4 per (mi,ni)
    #pragma unroll
    for (int mi = 0; mi < 4; mi++) {
      const int row = tm + wr * 64 + mi * 16 + 4 * lg;   // token index (j adds 0..3)
      const int n = row >> 11;
      const int s0 = (row & 2047) & ~63;
      const int cb = 32 * (mi >> 1) + 8 * lg + 4 * (mi & 1);
      #pragma unroll
      for (int ni = 0; ni < 4; ni++) {
        const int d = tn + wc * 64 + ni * 16 + lr;       // feature index
        const int nb = n * 16 + (d >> 6);
        half4 hv = __builtin_convertvector(acc[mi][ni], half4);
        *(half4*)(Vg2 + ((size_t)nb * 64 + (d & 63)) * SQ + s0 + cb) = hv;
      }
    }
  } else {
    _Float16* C = (z == 0) ? C0 : C1;
    const float sc = (z == 0) ? QSCALE : 1.0f;
    #pragma unroll
    for (int mi = 0; mi < 4; mi++) {
      const int row = tm + wr * 64 + mi * 16 + 4 * lg;
      #pragma unroll
      for (int ni = 0; ni < 4; ni++) {
        const int col = tn + wc * 64 + ni * 16 + lr;
        #pragma unroll
        for (int j = 0; j < 4; j++)
          C[(size_t)(row + j) * N + col] = (_Float16)(acc[mi][ni][j] * sc);
      }
    }
  }
}

// -------- Output GEMM: 64x128 tile, 2-phase dbuf, f32 + bias ---------------
__global__ __launch_bounds__(256, 3)
void gemm_o(const _Float16* __restrict__ A, const _Float16* __restrict__ B,
            float* __restrict__ Cf, const float* __restrict__ bias,
            int M, int N, int K)
{
  __shared__ _Float16 As[2][64 * 64];    // 16 KB
  __shared__ _Float16 Bs[2][128 * 64];   // 32 KB
  const int tid = threadIdx.x;
  const int w = tid >> 6, lane = tid & 63;
  const int lr = lane & 15, lg = lane >> 4;
  const int l8 = lane >> 3, l7 = lane & 7;
  const int gch = l7 ^ (l8 & 7);
  const int tm = blockIdx.x * 64, tn = blockIdx.y * 128;
  const int wr = w >> 1, wc = w & 1;   // wave = 32x64 quadrant
  const int sl7 = lr & 7;

  const _Float16* Ab = A + (size_t)(tm + w * 8 + l8) * K + gch * 8;
  const _Float16* Bb = B + (size_t)(tn + w * 8 + l8) * K + gch * 8;

  const f32x4 zv = {0.f, 0.f, 0.f, 0.f};
  f32x4 acc[2][4];
  #pragma unroll
  for (int mi = 0; mi < 2; mi++)
    #pragma unroll
    for (int ni = 0; ni < 4; ni++) acc[mi][ni] = zv;

  // prologue
  #pragma unroll
  for (int ci = 0; ci < 2; ci++)
    async16(Ab + (size_t)(ci * 32) * K, (void*)(As[0] + (w + ci * 4) * 512));
  #pragma unroll
  for (int ci = 0; ci < 4; ci++)
    async16(Bb + (size_t)(ci * 32) * K, (void*)(Bs[0] + (w + ci * 4) * 512));
  __syncthreads();

  int cur = 0;
  for (int ks = 0; ks < K; ks += 64) {
    if (ks + 64 < K) {
      const _Float16* An = Ab + ks + 64;
      const _Float16* Bn = Bb + ks + 64;
      #pragma unroll
      for (int ci = 0; ci < 2; ci++)
        async16(An + (size_t)(ci * 32) * K, (void*)(As[cur ^ 1] + (w + ci * 4) * 512));
      #pragma unroll
      for (int ci = 0; ci < 4; ci++)
        async16(Bn + (size_t)(ci * 32) * K, (void*)(Bs[cur ^ 1] + (w + ci * 4) * 512));
    }
    #pragma unroll
    for (int kk = 0; kk < 2; kk++) {
      const int sl = ((kk * 4 + lg) ^ sl7) << 4;
      half8 af[2], bf[4];
      #pragma unroll
      for (int mi = 0; mi < 2; mi++)
        af[mi] = *(const half8*)((const char*)As[cur] + (wr * 32 + mi * 16 + lr) * 128 + sl);
      #pragma unroll
      for (int ni = 0; ni < 4; ni++)
        bf[ni] = *(const half8*)((const char*)Bs[cur] + (wc * 64 + ni * 16 + lr) * 128 + sl);
      #pragma unroll
      for (int mi = 0; mi < 2; mi++)
        #pragma unroll
        for (int ni = 0; ni < 4; ni++)
          acc[mi][ni] = MFMA_F16(af[mi], bf[ni], acc[mi][ni]);
    }
    __syncthreads();
    cur ^= 1;
  }
  #pragma unroll
  for (int mi = 0; mi < 2; mi++) {
    const int row = tm + wr * 32 + mi * 16 + 4 * lg;
    #pragma unroll
    for (int ni = 0; ni < 4; ni++) {
      const int col = tn + wc * 64 + ni * 16 + lr;
      #pragma unroll
      for (int j = 0; j < 4; j++)
        Cf[(size_t)(row + j) * N + col] = acc[mi][ni][j] + bias[col];
    }
  }
}

// -------- Flash attention, swapped-operand form, 64 Q-rows per block -------
// Grid 1024 blocks (4/CU). S^T = mfma(K, Q): lane owns q-col = lane&15 and a
// 16-value kv slice -> softmax = in-lane tree + shfl_xor(16,32). P packed
// in-register via cvt_pkrtz; PV k-mapping matched by Vg2's column permutation.
// Defer-max: skip O-rescale while the running max grows < 8 (exp2 domain).
__global__ __launch_bounds__(256, 4)
void attn_kernel(const _Float16* __restrict__ Q, const _Float16* __restrict__ Kg,
                 const _Float16* __restrict__ Vg2, _Float16* __restrict__ Og)
{
  __shared__ _Float16 Ks[2][64 * 64];
  __shared__ _Float16 Vt[2][64 * 64];
  const int tid = threadIdx.x;
  const int w = tid >> 6, lane = tid & 63;
  const int lr = lane & 15, lg = lane >> 4;
  const int l8 = lane >> 3, l7 = lane & 7;
  // bijective XCD swizzle: 1024 blocks, 128 per XCD => 4 heads per XCD L2
  const int id = blockIdx.x + 32 * blockIdx.y;
  const int wid = (id & 7) * 128 + (id >> 3);
  const int qb = wid & 31, nb = wid >> 5;
  const size_t hb  = (size_t)(nb >> 4) * SQ * E + (size_t)(nb & 15) * 64;
  const size_t hb2 = (size_t)nb * 64 * SQ;
  const int qbase = qb * 64 + w * 16;
  const int gsl = (l7 ^ (l8 & 7)) * 8;    // pre-swizzled global slot (elems)
  const int sl7 = lr & 7;

  // per-thread staging bases.  K rows are kv positions (stride E);
  // V rows are features d (stride SQ) and kv enters as a COLUMN offset.
  const _Float16* Kb = Kg  + hb  + (size_t)(w * 8 + l8) * E  + gsl;
  const _Float16* Vb = Vg2 + hb2 + (size_t)(w * 8 + l8) * SQ + gsl;

  // Q B-frags in registers (already scaled by QSCALE in the projection GEMM)
  half8 qf[2];
  #pragma unroll
  for (int kd = 0; kd < 2; kd++)
    qf[kd] = *(const half8*)(Q + hb + (size_t)(qbase + lr) * E + kd * 32 + lg * 8);

  const f32x4 zv = {0.f, 0.f, 0.f, 0.f};
  f32x4 o[4];
  float ms = -1e30f, ls = 0.f;
  #pragma unroll
  for (int nd = 0; nd < 4; nd++) o[nd] = zv;

  // prologue: stage tile 0 into buffer 0
  #pragma unroll
  for (int ci = 0; ci < 2; ci++) {
    async16(Kb + (size_t)(ci * 32) * E,  (void*)(Ks[0] + (w + ci * 4) * 512));
    async16(Vb + (size_t)(ci * 32) * SQ, (void*)(Vt[0] + (w + ci * 4) * 512));
  }
  __syncthreads();

  int cur = 0;
  for (int t = 0; t < 32; t++) {
    if (t < 31) {     // issue next-tile staging early
      const int kvb = (t + 1) * 64;
      #pragma unroll
      for (int ci = 0; ci < 2; ci++) {
        async16(Kb + (size_t)(kvb + ci * 32) * E,  (void*)(Ks[cur ^ 1] + (w + ci * 4) * 512));
        async16(Vb + (size_t)(ci * 32) * SQ + kvb, (void*)(Vt[cur ^ 1] + (w + ci * 4) * 512));
      }
    }
    // S^T = K Q^T (exp2-domain scaled): s[ni] rows kv=16ni+4lg+j, col q=lr
    f32x4 s[4];
    #pragma unroll
    for (int ni = 0; ni < 4; ni++) s[ni] = zv;
    __builtin_amdgcn_s_setprio(1);
    #pragma unroll
    for (int kd = 0; kd < 2; kd++) {
      const int sl = ((kd * 4 + lg) ^ sl7) << 4;
      half8 kf[4];
      #pragma unroll
      for (int ni = 0; ni < 4; ni++)
        kf[ni] = *(const half8*)((const char*)Ks[cur] + (ni * 16 + lr) * 128 + sl);
      #pragma unroll
      for (int ni = 0; ni < 4; ni++)
        s[ni] = MFMA_F16(kf[ni], qf[kd], s[ni]);
    }
    __builtin_amdgcn_s_setprio(0);
    // online softmax (exp2 domain), defer-max
    {
      float m0 = fmaxf(fmaxf(s[0][0], s[0][1]), fmaxf(s[0][2], s[0][3]));
      float m1 = fmaxf(fmaxf(s[1][0], s[1][1]), fmaxf(s[1][2], s[1][3]));
      float m2 = fmaxf(fmaxf(s[2][0], s[2][1]), fmaxf(s[2][2], s[2][3]));
      float m3 = fmaxf(fmaxf(s[3][0], s[3][1]), fmaxf(s[3][2], s[3][3]));
      float mx = fmaxf(fmaxf(m0, m1), fmaxf(m2, m3));
      mx = fmaxf(mx, __shfl_xor(mx, 16));
      mx = fmaxf(mx, __shfl_xor(mx, 32));
      if (__all(mx <= ms + 8.0f)) {
        // keep old max; P bounded by 2^8
        float rs = 0.f;
        #pragma unroll
        for (int ni = 0; ni < 4; ni++)
          #pragma unroll
          for (int jr = 0; jr < 4; jr++) {
            float p = EXP2(s[ni][jr] - ms);
            s[ni][jr] = p; rs += p;
          }
        rs += __shfl_xor(rs, 16);
        rs += __shfl_xor(rs, 32);
        ls += rs;
      } else {
        float mnew = fmaxf(ms, mx);
        float corr = EXP2(ms - mnew);
        ms = mnew;
        float rs = 0.f;
        #pragma unroll
        for (int ni = 0; ni < 4; ni++)
          #pragma unroll
          for (int jr = 0; jr < 4; jr++) {
            float p = EXP2(s[ni][jr] - ms);
            s[ni][jr] = p; rs += p;
          }
        rs += __shfl_xor(rs, 16);
        rs += __shfl_xor(rs, 32);
        ls = ls * corr + rs;
        // rescale O: corr lives at lane q=lr; O-row q = 4lg+jr
        #pragma unroll
        for (int jr = 0; jr < 4; jr++) {
          float c4 = bperm_f(4 * lg + jr, corr);
          #pragma unroll
          for (int nd = 0; nd < 4; nd++) o[nd][jr] *= c4;
        }
      }
    }
    // pack P A-frags in-lane via cvt_pkrtz: k-slot j' at kk -> kv = 32kk+16(j'>>2)+4lg+(j'&3)
    half8 pa[2];
    #pragma unroll
    for (int kk = 0; kk < 2; kk++) {
      union { half8 h8; fp16x2 h2[4]; } u;
      u.h2[0] = __builtin_amdgcn_cvt_pkrtz(s[2 * kk][0], s[2 * kk][1]);
      u.h2[1] = __builtin_amdgcn_cvt_pkrtz(s[2 * kk][2], s[2 * kk][3]);
      u.h2[2] = __builtin_amdgcn_cvt_pkrtz(s[2 * kk + 1][0], s[2 * kk + 1][1]);
      u.h2[3] = __builtin_amdgcn_cvt_pkrtz(s[2 * kk + 1][2], s[2 * kk + 1][3]);
      pa[kk] = u.h8;
    }
    // O += P V  (B-frags from permuted Vt; same read pattern as kf)
    __builtin_amdgcn_s_setprio(1);
    #pragma unroll
    for (int kk = 0; kk < 2; kk++) {
      const int sl = ((kk * 4 + lg) ^ sl7) << 4;
      half8 vf[4];
      #pragma unroll
      for (int nd = 0; nd < 4; nd++)
        vf[nd] = *(const half8*)((const char*)Vt[cur] + (nd * 16 + lr) * 128 + sl);
      #pragma unroll
      for (int nd = 0; nd < 4; nd++)
        o[nd] = MFMA_F16(pa[kk], vf[nd], o[nd]);
    }
    __builtin_amdgcn_s_setprio(0);
    __syncthreads();
    cur ^= 1;
  }
  // epilogue: O /= l (1/l redistributed like corr)
  {
    float li = 1.0f / ls;
    #pragma unroll
    for (int jr = 0; jr < 4; jr++) {
      float lv = bperm_f(4 * lg + jr, li);
      const int row = qbase + 4 * lg + jr;
      #pragma unroll
      for (int nd = 0; nd < 4; nd++)
        Og[hb + (size_t)row * E + nd * 16 + lr] = (_Float16)(o[nd][jr] * lv);
    }
  }
}

extern "C" void kernel_launch(void* const* d_in, const int* in_sizes, int n_in,
                              void* d_out, int out_size, void* d_ws, size_t ws_size,
                              hipStream_t stream)
{
  const float* x  = (const float*)d_in[0];
  const float* Wq = (const float*)d_in[1];
  const float* Wk = (const float*)d_in[2];
  const float* Wv = (const float*)d_in[3];
  const float* Wo = (const float*)d_in[4];
  const float* bo = (const float*)d_in[5];
  char* ws = (char*)d_ws;
  const size_t MB = 1024u * 1024u;
  // ws layout (32 MiB): [0,8) xh | [8,16) weights f16 | [16,24) Vg2 | [24,32) Oh
  _Float16* xh  = (_Float16*)(ws);
  _Float16* Wqh = (_Float16*)(ws + 8 * MB);
  _Float16* Wkh = (_Float16*)(ws + 10 * MB);
  _Float16* Wvh = (_Float16*)(ws + 12 * MB);
  _Float16* Woh = (_Float16*)(ws + 14 * MB);
  _Float16* Vg2 = (_Float16*)(ws + 16 * MB);
  _Float16* Oh  = (_Float16*)(ws + 24 * MB);
  // Q and K parked in d_out (dead before final GEMM overwrites it)
  _Float16* Qh  = (_Float16*)(d_out);
  _Float16* Kh  = (_Float16*)((char*)d_out + 8 * MB);
  float* Y = (float*)d_out;

  cvtall<<<8192, 256, 0, stream>>>(x, Wq, Wk, Wv, Wo, xh, Wqh, Wkh, Wvh, Woh);

  gemm_qkv<<<dim3(32, 8, 3), 256, 0, stream>>>(
      xh, Wqh, Wkh, Wvh, Qh, Kh, Vg2, NR, E, E);

  attn_kernel<<<dim3(32, 32), 256, 0, stream>>>(Qh, Kh, Vg2, Oh);

  gemm_o<<<dim3(64, 8), 256, 0, stream>>>(Oh, Woh, Y, bo, NR, E, E);
}

// Round 9
// 193.467 us; speedup vs baseline: 1.0221x; 1.0221x over previous
//
#include <hip/hip_runtime.h>

// Problem constants
#define E   1024
#define SQ  2048
#define NR  4096    // N*S rows

typedef _Float16 half8  __attribute__((ext_vector_type(8)));
typedef _Float16 half4  __attribute__((ext_vector_type(4)));
typedef __fp16   fp16x2 __attribute__((ext_vector_type(2)));
typedef float    f32x4  __attribute__((ext_vector_type(4)));

#define MFMA_F16(a, b, c) __builtin_amdgcn_mfma_f32_16x16x32_f16((a), (b), (c), 0, 0, 0)

#if __has_builtin(__builtin_amdgcn_exp2f)
#define EXP2(x) __builtin_amdgcn_exp2f(x)
#else
#define EXP2(x) exp2f(x)
#endif

// Q pre-scale: (1/sqrt(E)) * log2(e) so softmax runs in exp2 domain
#define QSCALE 0.04508422002778011f

// async global->LDS, 16B per lane. LDS dest is wave-uniform base + lane*16.
__device__ __forceinline__ void async16(const void* g, void* l) {
  __builtin_amdgcn_global_load_lds((const __attribute__((address_space(1))) void*)g,
                                   (__attribute__((address_space(3))) void*)l, 16, 0, 0);
}

__device__ __forceinline__ float bperm_f(int srclane, float v) {
  return __int_as_float(__builtin_amdgcn_ds_bpermute(srclane << 2, __float_as_int(v)));
}

// -------- f32 -> f16 convert, all 5 tensors in one launch ------------------
__global__ __launch_bounds__(256)
void cvtall(const float* __restrict__ x, const float* __restrict__ wq,
            const float* __restrict__ wk, const float* __restrict__ wv,
            const float* __restrict__ wo,
            _Float16* __restrict__ xh, _Float16* __restrict__ wqh,
            _Float16* __restrict__ wkh, _Float16* __restrict__ wvh,
            _Float16* __restrict__ woh) {
  int b = blockIdx.x;
  const float* src; _Float16* dst; int off;
  if (b < 4096)      { src = x;  dst = xh;  off = b; }
  else if (b < 5120) { src = wq; dst = wqh; off = b - 4096; }
  else if (b < 6144) { src = wk; dst = wkh; off = b - 5120; }
  else if (b < 7168) { src = wv; dst = wvh; off = b - 6144; }
  else               { src = wo; dst = woh; off = b - 7168; }
  int i = off * 256 + threadIdx.x;
  f32x4 v = ((const f32x4*)src)[i];
  ((half4*)dst)[i] = __builtin_convertvector(v, half4);
}

// -------- QKV GEMM: 128x128 tile, BK=32, 2-phase dbuf, 32 KB LDS (3 blk/CU)
// z=0: Q (scaled by QSCALE), z=1: K, z=2: V written transposed+permuted into
// Vg2[(n*16+h)*64 + d][s0 + c] where c = 32kk+8lg+4h'+jr <-> kv = 32kk+16h'+4lg+jr.
// LDS rows are 64 B (32 f16); swizzle: 16B-slot ^= (row & 3); staging source
// pre-swizzled so global_load_lds' linear dest lands swizzled.
__global__ __launch_bounds__(256, 3)
void gemm_qkv(const _Float16* __restrict__ A,
              const _Float16* __restrict__ B0, const _Float16* __restrict__ B1,
              const _Float16* __restrict__ B2,
              _Float16* __restrict__ C0, _Float16* __restrict__ C1,
              _Float16* __restrict__ Vg2,
              int M, int N, int K)
{
  const int z = blockIdx.z;
  const _Float16* B = (z == 0) ? B0 : ((z == 1) ? B1 : B2);
  __shared__ _Float16 As[2][128 * 32];   // 16 KB
  __shared__ _Float16 Bs[2][128 * 32];   // 16 KB
  const int tid = threadIdx.x;
  const int w = tid >> 6, lane = tid & 63;
  const int lr = lane & 15, lg = lane >> 4;
  const int tm = blockIdx.x * 128, tn = blockIdx.y * 128;
  const int wr = w >> 1, wc = w & 1;
  const int sl3 = lr & 3;

  // staging: chunk = 1 KB = 16 rows x 64 B; lane covers row (lane>>2), slot (lane&3)
  const int srow = lane >> 2;
  const int gsl = ((lane & 3) ^ (srow & 3)) * 8;   // pre-swizzled elem offset
  const _Float16* Ab = A + (size_t)(tm + w * 16 + srow) * K + gsl;
  const _Float16* Bb = B + (size_t)(tn + w * 16 + srow) * K + gsl;

  const f32x4 zv = {0.f, 0.f, 0.f, 0.f};
  f32x4 acc[4][4];
  #pragma unroll
  for (int mi = 0; mi < 4; mi++)
    #pragma unroll
    for (int ni = 0; ni < 4; ni++) acc[mi][ni] = zv;

  // prologue: stage ks=0 into buffer 0
  #pragma unroll
  for (int ci = 0; ci < 2; ci++) {
    async16(Ab + (size_t)(ci * 64) * K, (void*)(As[0] + (w + ci * 4) * 512));
    async16(Bb + (size_t)(ci * 64) * K, (void*)(Bs[0] + (w + ci * 4) * 512));
  }
  __syncthreads();

  int cur = 0;
  for (int ks = 0; ks < K; ks += 32) {
    if (ks + 32 < K) {    // issue next-tile staging before compute
      #pragma unroll
      for (int ci = 0; ci < 2; ci++) {
        async16(Ab + (size_t)(ci * 64) * K + ks + 32, (void*)(As[cur ^ 1] + (w + ci * 4) * 512));
        async16(Bb + (size_t)(ci * 64) * K + ks + 32, (void*)(Bs[cur ^ 1] + (w + ci * 4) * 512));
      }
    }
    half8 af[4], bf[4];
    #pragma unroll
    for (int mi = 0; mi < 4; mi++) {
      const int row = wr * 64 + mi * 16 + lr;
      af[mi] = *(const half8*)((const char*)As[cur] + row * 64 + ((lg ^ sl3) << 4));
    }
    #pragma unroll
    for (int ni = 0; ni < 4; ni++) {
      const int row = wc * 64 + ni * 16 + lr;
      bf[ni] = *(const half8*)((const char*)Bs[cur] + row * 64 + ((lg ^ sl3) << 4));
    }
    #pragma unroll
    for (int mi = 0; mi < 4; mi++)
      #pragma unroll
      for (int ni = 0; ni < 4; ni++)
        acc[mi][ni] = MFMA_F16(af[mi], bf[ni], acc[mi][ni]);
    __syncthreads();
    cur ^= 1;
  }
  if (z == 2) {
    // V permuted-transposed write, half4 per (mi,ni)
    #pragma unroll
    for (int mi = 0; mi < 4; mi++) {
      const int row = tm + wr * 64 + mi * 16 + 4 * lg;   // token index (j adds 0..3)
      const int n = row >> 11;
      const int s0 = (row & 2047) & ~63;
      const int cb = 32 * (mi >> 1) + 8 * lg + 4 * (mi & 1);
      #pragma unroll
      for (int ni = 0; ni < 4; ni++) {
        const int d = tn + wc * 64 + ni * 16 + lr;       // feature index
        const int nb = n * 16 + (d >> 6);
        half4 hv = __builtin_convertvector(acc[mi][ni], half4);
        *(half4*)(Vg2 + ((size_t)nb * 64 + (d & 63)) * SQ + s0 + cb) = hv;
      }
    }
  } else {
    _Float16* C = (z == 0) ? C0 : C1;
    const float sc = (z == 0) ? QSCALE : 1.0f;
    #pragma unroll
    for (int mi = 0; mi < 4; mi++) {
      const int row = tm + wr * 64 + mi * 16 + 4 * lg;
      #pragma unroll
      for (int ni = 0; ni < 4; ni++) {
        const int col = tn + wc * 64 + ni * 16 + lr;
        #pragma unroll
        for (int j = 0; j < 4; j++)
          C[(size_t)(row + j) * N + col] = (_Float16)(acc[mi][ni][j] * sc);
      }
    }
  }
}

// -------- Output GEMM: 64x128 tile, 2-phase dbuf, f32 + bias ---------------
__global__ __launch_bounds__(256, 2)
void gemm_o(const _Float16* __restrict__ A, const _Float16* __restrict__ B,
            float* __restrict__ Cf, const float* __restrict__ bias,
            int M, int N, int K)
{
  __shared__ _Float16 As[2][64 * 64];    // 16 KB
  __shared__ _Float16 Bs[2][128 * 64];   // 32 KB
  const int tid = threadIdx.x;
  const int w = tid >> 6, lane = tid & 63;
  const int lr = lane & 15, lg = lane >> 4;
  const int l8 = lane >> 3, l7 = lane & 7;
  const int gch = l7 ^ (l8 & 7);
  const int tm = blockIdx.x * 64, tn = blockIdx.y * 128;
  const int wr = w >> 1, wc = w & 1;   // wave = 32x64 quadrant
  const int sl7 = lr & 7;

  const _Float16* Ab = A + (size_t)(tm + w * 8 + l8) * K + gch * 8;
  const _Float16* Bb = B + (size_t)(tn + w * 8 + l8) * K + gch * 8;

  const f32x4 zv = {0.f, 0.f, 0.f, 0.f};
  f32x4 acc[2][4];
  #pragma unroll
  for (int mi = 0; mi < 2; mi++)
    #pragma unroll
    for (int ni = 0; ni < 4; ni++) acc[mi][ni] = zv;

  // prologue
  #pragma unroll
  for (int ci = 0; ci < 2; ci++)
    async16(Ab + (size_t)(ci * 32) * K, (void*)(As[0] + (w + ci * 4) * 512));
  #pragma unroll
  for (int ci = 0; ci < 4; ci++)
    async16(Bb + (size_t)(ci * 32) * K, (void*)(Bs[0] + (w + ci * 4) * 512));
  __syncthreads();

  int cur = 0;
  for (int ks = 0; ks < K; ks += 64) {
    if (ks + 64 < K) {
      const _Float16* An = Ab + ks + 64;
      const _Float16* Bn = Bb + ks + 64;
      #pragma unroll
      for (int ci = 0; ci < 2; ci++)
        async16(An + (size_t)(ci * 32) * K, (void*)(As[cur ^ 1] + (w + ci * 4) * 512));
      #pragma unroll
      for (int ci = 0; ci < 4; ci++)
        async16(Bn + (size_t)(ci * 32) * K, (void*)(Bs[cur ^ 1] + (w + ci * 4) * 512));
    }
    #pragma unroll
    for (int kk = 0; kk < 2; kk++) {
      const int sl = ((kk * 4 + lg) ^ sl7) << 4;
      half8 af[2], bf[4];
      #pragma unroll
      for (int mi = 0; mi < 2; mi++)
        af[mi] = *(const half8*)((const char*)As[cur] + (wr * 32 + mi * 16 + lr) * 128 + sl);
      #pragma unroll
      for (int ni = 0; ni < 4; ni++)
        bf[ni] = *(const half8*)((const char*)Bs[cur] + (wc * 64 + ni * 16 + lr) * 128 + sl);
      #pragma unroll
      for (int mi = 0; mi < 2; mi++)
        #pragma unroll
        for (int ni = 0; ni < 4; ni++)
          acc[mi][ni] = MFMA_F16(af[mi], bf[ni], acc[mi][ni]);
    }
    __syncthreads();
    cur ^= 1;
  }
  #pragma unroll
  for (int mi = 0; mi < 2; mi++) {
    const int row = tm + wr * 32 + mi * 16 + 4 * lg;
    #pragma unroll
    for (int ni = 0; ni < 4; ni++) {
      const int col = tn + wc * 64 + ni * 16 + lr;
      #pragma unroll
      for (int j = 0; j < 4; j++)
        Cf[(size_t)(row + j) * N + col] = acc[mi][ni][j] + bias[col];
    }
  }
}

// -------- Flash attention, swapped-operand form, 64 Q-rows per block -------
// Grid 1024 blocks (4/CU). S^T = mfma(K, Q): lane owns q-col = lane&15 and a
// 16-value kv slice -> softmax = in-lane tree + shfl_xor(16,32). P packed
// in-register via cvt_pkrtz; PV k-mapping matched by Vg2's column permutation.
// Defer-max: skip O-rescale while the running max grows < 8 (exp2 domain).
__global__ __launch_bounds__(256, 4)
void attn_kernel(const _Float16* __restrict__ Q, const _Float16* __restrict__ Kg,
                 const _Float16* __restrict__ Vg2, _Float16* __restrict__ Og)
{
  __shared__ _Float16 Ks[2][64 * 64];
  __shared__ _Float16 Vt[2][64 * 64];
  const int tid = threadIdx.x;
  const int w = tid >> 6, lane = tid & 63;
  const int lr = lane & 15, lg = lane >> 4;
  const int l8 = lane >> 3, l7 = lane & 7;
  // bijective XCD swizzle: 1024 blocks, 128 per XCD => 4 heads per XCD L2
  const int id = blockIdx.x + 32 * blockIdx.y;
  const int wid = (id & 7) * 128 + (id >> 3);
  const int qb = wid & 31, nb = wid >> 5;
  const size_t hb  = (size_t)(nb >> 4) * SQ * E + (size_t)(nb & 15) * 64;
  const size_t hb2 = (size_t)nb * 64 * SQ;
  const int qbase = qb * 64 + w * 16;
  const int gsl = (l7 ^ (l8 & 7)) * 8;    // pre-swizzled global slot (elems)
  const int sl7 = lr & 7;

  // per-thread staging bases.  K rows are kv positions (stride E);
  // V rows are features d (stride SQ) and kv enters as a COLUMN offset.
  const _Float16* Kb = Kg  + hb  + (size_t)(w * 8 + l8) * E  + gsl;
  const _Float16* Vb = Vg2 + hb2 + (size_t)(w * 8 + l8) * SQ + gsl;

  // Q B-frags in registers (already scaled by QSCALE in the projection GEMM)
  half8 qf[2];
  #pragma unroll
  for (int kd = 0; kd < 2; kd++)
    qf[kd] = *(const half8*)(Q + hb + (size_t)(qbase + lr) * E + kd * 32 + lg * 8);

  const f32x4 zv = {0.f, 0.f, 0.f, 0.f};
  f32x4 o[4];
  float ms = -1e30f, ls = 0.f;
  #pragma unroll
  for (int nd = 0; nd < 4; nd++) o[nd] = zv;

  // prologue: stage tile 0 into buffer 0
  #pragma unroll
  for (int ci = 0; ci < 2; ci++) {
    async16(Kb + (size_t)(ci * 32) * E,  (void*)(Ks[0] + (w + ci * 4) * 512));
    async16(Vb + (size_t)(ci * 32) * SQ, (void*)(Vt[0] + (w + ci * 4) * 512));
  }
  __syncthreads();

  int cur = 0;
  for (int t = 0; t < 32; t++) {
    if (t < 31) {     // issue next-tile staging early
      const int kvb = (t + 1) * 64;
      #pragma unroll
      for (int ci = 0; ci < 2; ci++) {
        async16(Kb + (size_t)(kvb + ci * 32) * E,  (void*)(Ks[cur ^ 1] + (w + ci * 4) * 512));
        async16(Vb + (size_t)(ci * 32) * SQ + kvb, (void*)(Vt[cur ^ 1] + (w + ci * 4) * 512));
      }
    }
    // S^T = K Q^T (exp2-domain scaled): s[ni] rows kv=16ni+4lg+j, col q=lr
    f32x4 s[4];
    #pragma unroll
    for (int ni = 0; ni < 4; ni++) s[ni] = zv;
    __builtin_amdgcn_s_setprio(1);
    #pragma unroll
    for (int kd = 0; kd < 2; kd++) {
      const int sl = ((kd * 4 + lg) ^ sl7) << 4;
      half8 kf[4];
      #pragma unroll
      for (int ni = 0; ni < 4; ni++)
        kf[ni] = *(const half8*)((const char*)Ks[cur] + (ni * 16 + lr) * 128 + sl);
      #pragma unroll
      for (int ni = 0; ni < 4; ni++)
        s[ni] = MFMA_F16(kf[ni], qf[kd], s[ni]);
    }
    __builtin_amdgcn_s_setprio(0);
    // online softmax (exp2 domain), defer-max
    {
      float m0 = fmaxf(fmaxf(s[0][0], s[0][1]), fmaxf(s[0][2], s[0][3]));
      float m1 = fmaxf(fmaxf(s[1][0], s[1][1]), fmaxf(s[1][2], s[1][3]));
      float m2 = fmaxf(fmaxf(s[2][0], s[2][1]), fmaxf(s[2][2], s[2][3]));
      float m3 = fmaxf(fmaxf(s[3][0], s[3][1]), fmaxf(s[3][2], s[3][3]));
      float mx = fmaxf(fmaxf(m0, m1), fmaxf(m2, m3));
      mx = fmaxf(mx, __shfl_xor(mx, 16));
      mx = fmaxf(mx, __shfl_xor(mx, 32));
      if (__all(mx <= ms + 8.0f)) {
        // keep old max; P bounded by 2^8
        float rs = 0.f;
        #pragma unroll
        for (int ni = 0; ni < 4; ni++)
          #pragma unroll
          for (int jr = 0; jr < 4; jr++) {
            float p = EXP2(s[ni][jr] - ms);
            s[ni][jr] = p; rs += p;
          }
        rs += __shfl_xor(rs, 16);
        rs += __shfl_xor(rs, 32);
        ls += rs;
      } else {
        float mnew = fmaxf(ms, mx);
        float corr = EXP2(ms - mnew);
        ms = mnew;
        float rs = 0.f;
        #pragma unroll
        for (int ni = 0; ni < 4; ni++)
          #pragma unroll
          for (int jr = 0; jr < 4; jr++) {
            float p = EXP2(s[ni][jr] - ms);
            s[ni][jr] = p; rs += p;
          }
        rs += __shfl_xor(rs, 16);
        rs += __shfl_xor(rs, 32);
        ls = ls * corr + rs;
        // rescale O: corr lives at lane q=lr; O-row q = 4lg+jr
        #pragma unroll
        for (int jr = 0; jr < 4; jr++) {
          float c4 = bperm_f(4 * lg + jr, corr);
          #pragma unroll
          for (int nd = 0; nd < 4; nd++) o[nd][jr] *= c4;
        }
      }
    }
    // pack P A-frags in-lane via cvt_pkrtz: k-slot j' at kk -> kv = 32kk+16(j'>>2)+4lg+(j'&3)
    half8 pa[2];
    #pragma unroll
    for (int kk = 0; kk < 2; kk++) {
      union { half8 h8; fp16x2 h2[4]; } u;
      u.h2[0] = __builtin_amdgcn_cvt_pkrtz(s[2 * kk][0], s[2 * kk][1]);
      u.h2[1] = __builtin_amdgcn_cvt_pkrtz(s[2 * kk][2], s[2 * kk][3]);
      u.h2[2] = __builtin_amdgcn_cvt_pkrtz(s[2 * kk + 1][0], s[2 * kk + 1][1]);
      u.h2[3] = __builtin_amdgcn_cvt_pkrtz(s[2 * kk + 1][2], s[2 * kk + 1][3]);
      pa[kk] = u.h8;
    }
    // O += P V  (B-frags from permuted Vt; same read pattern as kf)
    __builtin_amdgcn_s_setprio(1);
    #pragma unroll
    for (int kk = 0; kk < 2; kk++) {
      const int sl = ((kk * 4 + lg) ^ sl7) << 4;
      half8 vf[4];
      #pragma unroll
      for (int nd = 0; nd < 4; nd++)
        vf[nd] = *(const half8*)((const char*)Vt[cur] + (nd * 16 + lr) * 128 + sl);
      #pragma unroll
      for (int nd = 0; nd < 4; nd++)
        o[nd] = MFMA_F16(pa[kk], vf[nd], o[nd]);
    }
    __builtin_amdgcn_s_setprio(0);
    __syncthreads();
    cur ^= 1;
  }
  // epilogue: O /= l (1/l redistributed like corr)
  {
    float li = 1.0f / ls;
    #pragma unroll
    for (int jr = 0; jr < 4; jr++) {
      float lv = bperm_f(4 * lg + jr, li);
      const int row = qbase + 4 * lg + jr;
      #pragma unroll
      for (int nd = 0; nd < 4; nd++)
        Og[hb + (size_t)row * E + nd * 16 + lr] = (_Float16)(o[nd][jr] * lv);
    }
  }
}

extern "C" void kernel_launch(void* const* d_in, const int* in_sizes, int n_in,
                              void* d_out, int out_size, void* d_ws, size_t ws_size,
                              hipStream_t stream)
{
  const float* x  = (const float*)d_in[0];
  const float* Wq = (const float*)d_in[1];
  const float* Wk = (const float*)d_in[2];
  const float* Wv = (const float*)d_in[3];
  const float* Wo = (const float*)d_in[4];
  const float* bo = (const float*)d_in[5];
  char* ws = (char*)d_ws;
  const size_t MB = 1024u * 1024u;
  // ws layout (32 MiB): [0,8) xh | [8,16) weights f16 | [16,24) Vg2 | [24,32) Oh
  _Float16* xh  = (_Float16*)(ws);
  _Float16* Wqh = (_Float16*)(ws + 8 * MB);
  _Float16* Wkh = (_Float16*)(ws + 10 * MB);
  _Float16* Wvh = (_Float16*)(ws + 12 * MB);
  _Float16* Woh = (_Float16*)(ws + 14 * MB);
  _Float16* Vg2 = (_Float16*)(ws + 16 * MB);
  _Float16* Oh  = (_Float16*)(ws + 24 * MB);
  // Q and K parked in d_out (dead before final GEMM overwrites it)
  _Float16* Qh  = (_Float16*)(d_out);
  _Float16* Kh  = (_Float16*)((char*)d_out + 8 * MB);
  float* Y = (float*)d_out;

  cvtall<<<8192, 256, 0, stream>>>(x, Wq, Wk, Wv, Wo, xh, Wqh, Wkh, Wvh, Woh);

  gemm_qkv<<<dim3(32, 8, 3), 256, 0, stream>>>(
      xh, Wqh, Wkh, Wvh, Qh, Kh, Vg2, NR, E, E);

  attn_kernel<<<dim3(32, 32), 256, 0, stream>>>(Qh, Kh, Vg2, Oh);

  gemm_o<<<dim3(64, 8), 256, 0, stream>>>(Oh, Woh, Y, bo, NR, E, E);
}

// Round 10
// 192.901 us; speedup vs baseline: 1.0251x; 1.0029x over previous
//
#include <hip/hip_runtime.h>

// Problem constants
#define E   1024
#define SQ  2048
#define NR  4096    // N*S rows

typedef _Float16 half8  __attribute__((ext_vector_type(8)));
typedef _Float16 half4  __attribute__((ext_vector_type(4)));
typedef __fp16   fp16x2 __attribute__((ext_vector_type(2)));
typedef float    f32x4  __attribute__((ext_vector_type(4)));

#define MFMA_F16(a, b, c) __builtin_amdgcn_mfma_f32_16x16x32_f16((a), (b), (c), 0, 0, 0)

#if __has_builtin(__builtin_amdgcn_exp2f)
#define EXP2(x) __builtin_amdgcn_exp2f(x)
#else
#define EXP2(x) exp2f(x)
#endif

// Q pre-scale: (1/sqrt(E)) * log2(e) so softmax runs in exp2 domain
#define QSCALE 0.04508422002778011f

// async global->LDS, 16B per lane. LDS dest is wave-uniform base + lane*16.
__device__ __forceinline__ void async16(const void* g, void* l) {
  __builtin_amdgcn_global_load_lds((const __attribute__((address_space(1))) void*)g,
                                   (__attribute__((address_space(3))) void*)l, 16, 0, 0);
}

__device__ __forceinline__ float bperm_f(int srclane, float v) {
  return __int_as_float(__builtin_amdgcn_ds_bpermute(srclane << 2, __float_as_int(v)));
}

// -------- f32 -> f16 convert, all 5 tensors in one launch ------------------
__global__ __launch_bounds__(256)
void cvtall(const float* __restrict__ x, const float* __restrict__ wq,
            const float* __restrict__ wk, const float* __restrict__ wv,
            const float* __restrict__ wo,
            _Float16* __restrict__ xh, _Float16* __restrict__ wqh,
            _Float16* __restrict__ wkh, _Float16* __restrict__ wvh,
            _Float16* __restrict__ woh) {
  int b = blockIdx.x;
  const float* src; _Float16* dst; int off;
  if (b < 4096)      { src = x;  dst = xh;  off = b; }
  else if (b < 5120) { src = wq; dst = wqh; off = b - 4096; }
  else if (b < 6144) { src = wk; dst = wkh; off = b - 5120; }
  else if (b < 7168) { src = wv; dst = wvh; off = b - 6144; }
  else               { src = wo; dst = woh; off = b - 7168; }
  int i = off * 256 + threadIdx.x;
  f32x4 v = ((const f32x4*)src)[i];
  ((half4*)dst)[i] = __builtin_convertvector(v, half4);
}

// -------- QKV GEMM: C[M,N] = A[M,K] * B[N,K]^T, 128x128 tile ---------------
// Single-buffered (R5 structure — dbuf measured neutral/worse at this shape).
// (256,3): cap VGPR so 3 blocks/CU are guaranteed -> all 768 blocks in ONE round.
// z=0: Q (scaled by QSCALE), z=1: K, z=2: V written transposed+permuted into
// Vg2[(n*16+h)*64 + d][s0 + c] where c = 32kk+8lg+4h'+jr <-> kv = 32kk+16h'+4lg+jr.
__global__ __launch_bounds__(256, 3)
void gemm_qkv(const _Float16* __restrict__ A,
              const _Float16* __restrict__ B0, const _Float16* __restrict__ B1,
              const _Float16* __restrict__ B2,
              _Float16* __restrict__ C0, _Float16* __restrict__ C1,
              _Float16* __restrict__ Vg2,
              int M, int N, int K)
{
  const int z = blockIdx.z;
  const _Float16* B = (z == 0) ? B0 : ((z == 1) ? B1 : B2);
  __shared__ _Float16 As[128 * 64];
  __shared__ _Float16 Bs[128 * 64];
  const int tid = threadIdx.x;
  const int w = tid >> 6, lane = tid & 63;
  const int lr = lane & 15, lg = lane >> 4;
  const int l8 = lane >> 3, l7 = lane & 7;
  const int gch = l7 ^ (l8 & 7);
  const int tm = blockIdx.x * 128, tn = blockIdx.y * 128;
  const int wr = w >> 1, wc = w & 1;
  const int sl7 = lr & 7;

  const f32x4 zv = {0.f, 0.f, 0.f, 0.f};
  f32x4 acc[4][4];
  #pragma unroll
  for (int mi = 0; mi < 4; mi++)
    #pragma unroll
    for (int ni = 0; ni < 4; ni++) acc[mi][ni] = zv;

  for (int ks = 0; ks < K; ks += 64) {
    #pragma unroll
    for (int ci = 0; ci < 4; ci++) {
      int c = w + ci * 4;
      async16(A + (size_t)(tm + c * 8 + l8) * K + ks + gch * 8, (void*)(As + c * 512));
    }
    #pragma unroll
    for (int ci = 0; ci < 4; ci++) {
      int c = w + ci * 4;
      async16(B + (size_t)(tn + c * 8 + l8) * K + ks + gch * 8, (void*)(Bs + c * 512));
    }
    __syncthreads();
    #pragma unroll
    for (int kk = 0; kk < 2; kk++) {
      const int sl = ((kk * 4 + lg) ^ sl7) << 4;
      half8 af[4], bf[4];
      #pragma unroll
      for (int mi = 0; mi < 4; mi++)
        af[mi] = *(const half8*)((const char*)As + (wr * 64 + mi * 16 + lr) * 128 + sl);
      #pragma unroll
      for (int ni = 0; ni < 4; ni++)
        bf[ni] = *(const half8*)((const char*)Bs + (wc * 64 + ni * 16 + lr) * 128 + sl);
      #pragma unroll
      for (int mi = 0; mi < 4; mi++)
        #pragma unroll
        for (int ni = 0; ni < 4; ni++)
          acc[mi][ni] = MFMA_F16(af[mi], bf[ni], acc[mi][ni]);
    }
    __syncthreads();
  }
  if (z == 2) {
    // V permuted-transposed write, half4 per (mi,ni)
    #pragma unroll
    for (int mi = 0; mi < 4; mi++) {
      const int row = tm + wr * 64 + mi * 16 + 4 * lg;   // token index (j adds 0..3)
      const int n = row >> 11;
      const int s0 = (row & 2047) & ~63;
      const int cb = 32 * (mi >> 1) + 8 * lg + 4 * (mi & 1);
      #pragma unroll
      for (int ni = 0; ni < 4; ni++) {
        const int d = tn + wc * 64 + ni * 16 + lr;       // feature index
        const int nb = n * 16 + (d >> 6);
        half4 hv = __builtin_convertvector(acc[mi][ni], half4);
        *(half4*)(Vg2 + ((size_t)nb * 64 + (d & 63)) * SQ + s0 + cb) = hv;
      }
    }
  } else {
    _Float16* C = (z == 0) ? C0 : C1;
    const float sc = (z == 0) ? QSCALE : 1.0f;
    #pragma unroll
    for (int mi = 0; mi < 4; mi++) {
      const int row = tm + wr * 64 + mi * 16 + 4 * lg;
      #pragma unroll
      for (int ni = 0; ni < 4; ni++) {
        const int col = tn + wc * 64 + ni * 16 + lr;
        #pragma unroll
        for (int j = 0; j < 4; j++)
          C[(size_t)(row + j) * N + col] = (_Float16)(acc[mi][ni][j] * sc);
      }
    }
  }
}

// -------- Output GEMM: 64x128 tile (512 blocks for occupancy), f32 + bias --
__global__ __launch_bounds__(256, 2)
void gemm_o(const _Float16* __restrict__ A, const _Float16* __restrict__ B,
            float* __restrict__ Cf, const float* __restrict__ bias,
            int M, int N, int K)
{
  __shared__ _Float16 As[64 * 64];    // 8 KB
  __shared__ _Float16 Bs[128 * 64];   // 16 KB
  const int tid = threadIdx.x;
  const int w = tid >> 6, lane = tid & 63;
  const int lr = lane & 15, lg = lane >> 4;
  const int l8 = lane >> 3, l7 = lane & 7;
  const int gch = l7 ^ (l8 & 7);
  const int tm = blockIdx.x * 64, tn = blockIdx.y * 128;
  const int wr = w >> 1, wc = w & 1;   // wave = 32x64 quadrant
  const int sl7 = lr & 7;

  const f32x4 zv = {0.f, 0.f, 0.f, 0.f};
  f32x4 acc[2][4];
  #pragma unroll
  for (int mi = 0; mi < 2; mi++)
    #pragma unroll
    for (int ni = 0; ni < 4; ni++) acc[mi][ni] = zv;

  for (int ks = 0; ks < K; ks += 64) {
    #pragma unroll
    for (int ci = 0; ci < 2; ci++) {          // A: 8 chunks
      int c = w + ci * 4;
      async16(A + (size_t)(tm + c * 8 + l8) * K + ks + gch * 8, (void*)(As + c * 512));
    }
    #pragma unroll
    for (int ci = 0; ci < 4; ci++) {          // B: 16 chunks
      int c = w + ci * 4;
      async16(B + (size_t)(tn + c * 8 + l8) * K + ks + gch * 8, (void*)(Bs + c * 512));
    }
    __syncthreads();
    #pragma unroll
    for (int kk = 0; kk < 2; kk++) {
      const int sl = ((kk * 4 + lg) ^ sl7) << 4;
      half8 af[2], bf[4];
      #pragma unroll
      for (int mi = 0; mi < 2; mi++)
        af[mi] = *(const half8*)((const char*)As + (wr * 32 + mi * 16 + lr) * 128 + sl);
      #pragma unroll
      for (int ni = 0; ni < 4; ni++)
        bf[ni] = *(const half8*)((const char*)Bs + (wc * 64 + ni * 16 + lr) * 128 + sl);
      #pragma unroll
      for (int mi = 0; mi < 2; mi++)
        #pragma unroll
        for (int ni = 0; ni < 4; ni++)
          acc[mi][ni] = MFMA_F16(af[mi], bf[ni], acc[mi][ni]);
    }
    __syncthreads();
  }
  #pragma unroll
  for (int mi = 0; mi < 2; mi++) {
    const int row = tm + wr * 32 + mi * 16 + 4 * lg;
    #pragma unroll
    for (int ni = 0; ni < 4; ni++) {
      const int col = tn + wc * 64 + ni * 16 + lr;
      #pragma unroll
      for (int j = 0; j < 4; j++)
        Cf[(size_t)(row + j) * N + col] = acc[mi][ni][j] + bias[col];
    }
  }
}

// -------- Flash attention, swapped-operand form, 64 Q-rows per block -------
// Grid 1024 blocks (4/CU). S^T = mfma(K, Q): lane owns q-col = lane&15 and a
// 16-value kv slice -> softmax = in-lane tree + shfl_xor(16,32). P packed
// in-register via cvt_pkrtz; PV k-mapping matched by Vg2's column permutation.
// Defer-max: skip O-rescale while the running max grows < 8 (exp2 domain).
__global__ __launch_bounds__(256, 4)
void attn_kernel(const _Float16* __restrict__ Q, const _Float16* __restrict__ Kg,
                 const _Float16* __restrict__ Vg2, _Float16* __restrict__ Og)
{
  __shared__ _Float16 Ks[2][64 * 64];
  __shared__ _Float16 Vt[2][64 * 64];
  const int tid = threadIdx.x;
  const int w = tid >> 6, lane = tid & 63;
  const int lr = lane & 15, lg = lane >> 4;
  const int l8 = lane >> 3, l7 = lane & 7;
  // bijective XCD swizzle: 1024 blocks, 128 per XCD => 4 heads per XCD L2
  const int id = blockIdx.x + 32 * blockIdx.y;
  const int wid = (id & 7) * 128 + (id >> 3);
  const int qb = wid & 31, nb = wid >> 5;
  const size_t hb  = (size_t)(nb >> 4) * SQ * E + (size_t)(nb & 15) * 64;
  const size_t hb2 = (size_t)nb * 64 * SQ;
  const int qbase = qb * 64 + w * 16;
  const int gsl = (l7 ^ (l8 & 7)) * 8;    // pre-swizzled global slot (elems)
  const int sl7 = lr & 7;

  // Q B-frags in registers (already scaled by QSCALE in the projection GEMM)
  half8 qf[2];
  #pragma unroll
  for (int kd = 0; kd < 2; kd++)
    qf[kd] = *(const half8*)(Q + hb + (size_t)(qbase + lr) * E + kd * 32 + lg * 8);

  const f32x4 zv = {0.f, 0.f, 0.f, 0.f};
  f32x4 o[4];
  float ms = -1e30f, ls = 0.f;
  #pragma unroll
  for (int nd = 0; nd < 4; nd++) o[nd] = zv;

  // prologue: stage tile 0 into buffer 0
  #pragma unroll
  for (int ci = 0; ci < 2; ci++) {
    int c = w + ci * 4;
    async16(Kg  + hb  + (size_t)(c * 8 + l8) * E  + gsl, (void*)(Ks[0] + c * 512));
    async16(Vg2 + hb2 + (size_t)(c * 8 + l8) * SQ + gsl, (void*)(Vt[0] + c * 512));
  }
  __syncthreads();

  int cur = 0;
  for (int t = 0; t < 32; t++) {
    if (t < 31) {     // issue next-tile staging early
      const int kvb = (t + 1) * 64;
      #pragma unroll
      for (int ci = 0; ci < 2; ci++) {
        int c = w + ci * 4;
        async16(Kg  + hb  + (size_t)(kvb + c * 8 + l8) * E + gsl, (void*)(Ks[cur ^ 1] + c * 512));
        async16(Vg2 + hb2 + (size_t)(c * 8 + l8) * SQ + kvb + gsl, (void*)(Vt[cur ^ 1] + c * 512));
      }
    }
    // S^T = K Q^T (exp2-domain scaled): s[ni] rows kv=16ni+4lg+j, col q=lr
    f32x4 s[4];
    #pragma unroll
    for (int ni = 0; ni < 4; ni++) s[ni] = zv;
    #pragma unroll
    for (int kd = 0; kd < 2; kd++) {
      const int sl = ((kd * 4 + lg) ^ sl7) << 4;
      half8 kf[4];
      #pragma unroll
      for (int ni = 0; ni < 4; ni++)
        kf[ni] = *(const half8*)((const char*)Ks[cur] + (ni * 16 + lr) * 128 + sl);
      #pragma unroll
      for (int ni = 0; ni < 4; ni++)
        s[ni] = MFMA_F16(kf[ni], qf[kd], s[ni]);
    }
    // online softmax (exp2 domain), defer-max
    {
      float m0 = fmaxf(fmaxf(s[0][0], s[0][1]), fmaxf(s[0][2], s[0][3]));
      float m1 = fmaxf(fmaxf(s[1][0], s[1][1]), fmaxf(s[1][2], s[1][3]));
      float m2 = fmaxf(fmaxf(s[2][0], s[2][1]), fmaxf(s[2][2], s[2][3]));
      float m3 = fmaxf(fmaxf(s[3][0], s[3][1]), fmaxf(s[3][2], s[3][3]));
      float mx = fmaxf(fmaxf(m0, m1), fmaxf(m2, m3));
      mx = fmaxf(mx, __shfl_xor(mx, 16));
      mx = fmaxf(mx, __shfl_xor(mx, 32));
      if (__all(mx <= ms + 8.0f)) {
        // keep old max; P bounded by 2^8
        float rs = 0.f;
        #pragma unroll
        for (int ni = 0; ni < 4; ni++)
          #pragma unroll
          for (int jr = 0; jr < 4; jr++) {
            float p = EXP2(s[ni][jr] - ms);
            s[ni][jr] = p; rs += p;
          }
        rs += __shfl_xor(rs, 16);
        rs += __shfl_xor(rs, 32);
        ls += rs;
      } else {
        float mnew = fmaxf(ms, mx);
        float corr = EXP2(ms - mnew);
        ms = mnew;
        float rs = 0.f;
        #pragma unroll
        for (int ni = 0; ni < 4; ni++)
          #pragma unroll
          for (int jr = 0; jr < 4; jr++) {
            float p = EXP2(s[ni][jr] - ms);
            s[ni][jr] = p; rs += p;
          }
        rs += __shfl_xor(rs, 16);
        rs += __shfl_xor(rs, 32);
        ls = ls * corr + rs;
        // rescale O: corr lives at lane q=lr; O-row q = 4lg+jr
        #pragma unroll
        for (int jr = 0; jr < 4; jr++) {
          float c4 = bperm_f(4 * lg + jr, corr);
          #pragma unroll
          for (int nd = 0; nd < 4; nd++) o[nd][jr] *= c4;
        }
      }
    }
    // pack P A-frags in-lane via cvt_pkrtz: k-slot j' at kk -> kv = 32kk+16(j'>>2)+4lg+(j'&3)
    half8 pa[2];
    #pragma unroll
    for (int kk = 0; kk < 2; kk++) {
      union { half8 h8; fp16x2 h2[4]; } u;
      u.h2[0] = __builtin_amdgcn_cvt_pkrtz(s[2 * kk][0], s[2 * kk][1]);
      u.h2[1] = __builtin_amdgcn_cvt_pkrtz(s[2 * kk][2], s[2 * kk][3]);
      u.h2[2] = __builtin_amdgcn_cvt_pkrtz(s[2 * kk + 1][0], s[2 * kk + 1][1]);
      u.h2[3] = __builtin_amdgcn_cvt_pkrtz(s[2 * kk + 1][2], s[2 * kk + 1][3]);
      pa[kk] = u.h8;
    }
    // O += P V  (B-frags from permuted Vt; same read pattern as kf)
    #pragma unroll
    for (int kk = 0; kk < 2; kk++) {
      const int sl = ((kk * 4 + lg) ^ sl7) << 4;
      half8 vf[4];
      #pragma unroll
      for (int nd = 0; nd < 4; nd++)
        vf[nd] = *(const half8*)((const char*)Vt[cur] + (nd * 16 + lr) * 128 + sl);
      #pragma unroll
      for (int nd = 0; nd < 4; nd++)
        o[nd] = MFMA_F16(pa[kk], vf[nd], o[nd]);
    }
    __syncthreads();
    cur ^= 1;
  }
  // epilogue: O /= l (1/l redistributed like corr)
  {
    float li = 1.0f / ls;
    #pragma unroll
    for (int jr = 0; jr < 4; jr++) {
      float lv = bperm_f(4 * lg + jr, li);
      const int row = qbase + 4 * lg + jr;
      #pragma unroll
      for (int nd = 0; nd < 4; nd++)
        Og[hb + (size_t)row * E + nd * 16 + lr] = (_Float16)(o[nd][jr] * lv);
    }
  }
}

extern "C" void kernel_launch(void* const* d_in, const int* in_sizes, int n_in,
                              void* d_out, int out_size, void* d_ws, size_t ws_size,
                              hipStream_t stream)
{
  const float* x  = (const float*)d_in[0];
  const float* Wq = (const float*)d_in[1];
  const float* Wk = (const float*)d_in[2];
  const float* Wv = (const float*)d_in[3];
  const float* Wo = (const float*)d_in[4];
  const float* bo = (const float*)d_in[5];
  char* ws = (char*)d_ws;
  const size_t MB = 1024u * 1024u;
  // ws layout (32 MiB): [0,8) xh | [8,16) weights f16 | [16,24) Vg2 | [24,32) Oh
  _Float16* xh  = (_Float16*)(ws);
  _Float16* Wqh = (_Float16*)(ws + 8 * MB);
  _Float16* Wkh = (_Float16*)(ws + 10 * MB);
  _Float16* Wvh = (_Float16*)(ws + 12 * MB);
  _Float16* Woh = (_Float16*)(ws + 14 * MB);
  _Float16* Vg2 = (_Float16*)(ws + 16 * MB);
  _Float16* Oh  = (_Float16*)(ws + 24 * MB);
  // Q and K parked in d_out (dead before final GEMM overwrites it)
  _Float16* Qh  = (_Float16*)(d_out);
  _Float16* Kh  = (_Float16*)((char*)d_out + 8 * MB);
  float* Y = (float*)d_out;

  cvtall<<<8192, 256, 0, stream>>>(x, Wq, Wk, Wv, Wo, xh, Wqh, Wkh, Wvh, Woh);

  gemm_qkv<<<dim3(32, 8, 3), 256, 0, stream>>>(
      xh, Wqh, Wkh, Wvh, Qh, Kh, Vg2, NR, E, E);

  attn_kernel<<<dim3(32, 32), 256, 0, stream>>>(Qh, Kh, Vg2, Oh);

  gemm_o<<<dim3(64, 8), 256, 0, stream>>>(Oh, Woh, Y, bo, NR, E, E);
}

// Round 11
// 185.427 us; speedup vs baseline: 1.0664x; 1.0403x over previous
//
#include <hip/hip_runtime.h>

// Problem constants
#define E   1024
#define SQ  2048
#define NR  4096    // N*S rows

typedef _Float16 half8  __attribute__((ext_vector_type(8)));
typedef _Float16 half4  __attribute__((ext_vector_type(4)));
typedef __fp16   fp16x2 __attribute__((ext_vector_type(2)));
typedef float    f32x4  __attribute__((ext_vector_type(4)));

#define MFMA_F16(a, b, c) __builtin_amdgcn_mfma_f32_16x16x32_f16((a), (b), (c), 0, 0, 0)

#if __has_builtin(__builtin_amdgcn_exp2f)
#define EXP2(x) __builtin_amdgcn_exp2f(x)
#else
#define EXP2(x) exp2f(x)
#endif

// Q pre-scale: (1/sqrt(E)) * log2(e) so softmax runs in exp2 domain
#define QSCALE 0.04508422002778011f

// async global->LDS, 16B per lane. LDS dest is wave-uniform base + lane*16.
__device__ __forceinline__ void async16(const void* g, void* l) {
  __builtin_amdgcn_global_load_lds((const __attribute__((address_space(1))) void*)g,
                                   (__attribute__((address_space(3))) void*)l, 16, 0, 0);
}

__device__ __forceinline__ float bperm_f(int srclane, float v) {
  return __int_as_float(__builtin_amdgcn_ds_bpermute(srclane << 2, __float_as_int(v)));
}

// -------- f32 -> f16 convert, all 5 tensors in one launch ------------------
__global__ __launch_bounds__(256)
void cvtall(const float* __restrict__ x, const float* __restrict__ wq,
            const float* __restrict__ wk, const float* __restrict__ wv,
            const float* __restrict__ wo,
            _Float16* __restrict__ xh, _Float16* __restrict__ wqh,
            _Float16* __restrict__ wkh, _Float16* __restrict__ wvh,
            _Float16* __restrict__ woh) {
  int b = blockIdx.x;
  const float* src; _Float16* dst; int off;
  if (b < 4096)      { src = x;  dst = xh;  off = b; }
  else if (b < 5120) { src = wq; dst = wqh; off = b - 4096; }
  else if (b < 6144) { src = wk; dst = wkh; off = b - 5120; }
  else if (b < 7168) { src = wv; dst = wvh; off = b - 6144; }
  else               { src = wo; dst = woh; off = b - 7168; }
  int i = off * 256 + threadIdx.x;
  f32x4 v = ((const f32x4*)src)[i];
  ((half4*)dst)[i] = __builtin_convertvector(v, half4);
}

// -------- QKV GEMM: C[M,N] = A[M,K] * B[N,K]^T, 128x128 tile (R5 form) -----
// z=0: Q (scaled by QSCALE), z=1: K, z=2: V written transposed+permuted into
// Vg2[(n*16+h)*64 + d][s0 + c] where c = 32kk+8lg+4h'+jr <-> kv = 32kk+16h'+4lg+jr.
__global__ __launch_bounds__(256, 2)
void gemm_qkv(const _Float16* __restrict__ A,
              const _Float16* __restrict__ B0, const _Float16* __restrict__ B1,
              const _Float16* __restrict__ B2,
              _Float16* __restrict__ C0, _Float16* __restrict__ C1,
              _Float16* __restrict__ Vg2,
              int M, int N, int K)
{
  const int z = blockIdx.z;
  const _Float16* B = (z == 0) ? B0 : ((z == 1) ? B1 : B2);
  __shared__ _Float16 As[128 * 64];
  __shared__ _Float16 Bs[128 * 64];
  const int tid = threadIdx.x;
  const int w = tid >> 6, lane = tid & 63;
  const int lr = lane & 15, lg = lane >> 4;
  const int l8 = lane >> 3, l7 = lane & 7;
  const int gch = l7 ^ (l8 & 7);
  const int tm = blockIdx.x * 128, tn = blockIdx.y * 128;
  const int wr = w >> 1, wc = w & 1;
  const int sl7 = lr & 7;

  const f32x4 zv = {0.f, 0.f, 0.f, 0.f};
  f32x4 acc[4][4];
  #pragma unroll
  for (int mi = 0; mi < 4; mi++)
    #pragma unroll
    for (int ni = 0; ni < 4; ni++) acc[mi][ni] = zv;

  for (int ks = 0; ks < K; ks += 64) {
    #pragma unroll
    for (int ci = 0; ci < 4; ci++) {
      int c = w + ci * 4;
      async16(A + (size_t)(tm + c * 8 + l8) * K + ks + gch * 8, (void*)(As + c * 512));
    }
    #pragma unroll
    for (int ci = 0; ci < 4; ci++) {
      int c = w + ci * 4;
      async16(B + (size_t)(tn + c * 8 + l8) * K + ks + gch * 8, (void*)(Bs + c * 512));
    }
    __syncthreads();
    #pragma unroll
    for (int kk = 0; kk < 2; kk++) {
      const int sl = ((kk * 4 + lg) ^ sl7) << 4;
      half8 af[4], bf[4];
      #pragma unroll
      for (int mi = 0; mi < 4; mi++)
        af[mi] = *(const half8*)((const char*)As + (wr * 64 + mi * 16 + lr) * 128 + sl);
      #pragma unroll
      for (int ni = 0; ni < 4; ni++)
        bf[ni] = *(const half8*)((const char*)Bs + (wc * 64 + ni * 16 + lr) * 128 + sl);
      #pragma unroll
      for (int mi = 0; mi < 4; mi++)
        #pragma unroll
        for (int ni = 0; ni < 4; ni++)
          acc[mi][ni] = MFMA_F16(af[mi], bf[ni], acc[mi][ni]);
    }
    __syncthreads();
  }
  if (z == 2) {
    // V permuted-transposed write, half4 per (mi,ni)
    #pragma unroll
    for (int mi = 0; mi < 4; mi++) {
      const int row = tm + wr * 64 + mi * 16 + 4 * lg;   // token index (j adds 0..3)
      const int n = row >> 11;
      const int s0 = (row & 2047) & ~63;
      const int cb = 32 * (mi >> 1) + 8 * lg + 4 * (mi & 1);
      #pragma unroll
      for (int ni = 0; ni < 4; ni++) {
        const int d = tn + wc * 64 + ni * 16 + lr;       // feature index
        const int nb = n * 16 + (d >> 6);
        half4 hv = __builtin_convertvector(acc[mi][ni], half4);
        *(half4*)(Vg2 + ((size_t)nb * 64 + (d & 63)) * SQ + s0 + cb) = hv;
      }
    }
  } else {
    _Float16* C = (z == 0) ? C0 : C1;
    const float sc = (z == 0) ? QSCALE : 1.0f;
    #pragma unroll
    for (int mi = 0; mi < 4; mi++) {
      const int row = tm + wr * 64 + mi * 16 + 4 * lg;
      #pragma unroll
      for (int ni = 0; ni < 4; ni++) {
        const int col = tn + wc * 64 + ni * 16 + lr;
        #pragma unroll
        for (int j = 0; j < 4; j++)
          C[(size_t)(row + j) * N + col] = (_Float16)(acc[mi][ni][j] * sc);
      }
    }
  }
}

// -------- Output GEMM: 64x128 tile (512 blocks for occupancy), f32 + bias --
__global__ __launch_bounds__(256, 2)
void gemm_o(const _Float16* __restrict__ A, const _Float16* __restrict__ B,
            float* __restrict__ Cf, const float* __restrict__ bias,
            int M, int N, int K)
{
  __shared__ _Float16 As[64 * 64];    // 8 KB
  __shared__ _Float16 Bs[128 * 64];   // 16 KB
  const int tid = threadIdx.x;
  const int w = tid >> 6, lane = tid & 63;
  const int lr = lane & 15, lg = lane >> 4;
  const int l8 = lane >> 3, l7 = lane & 7;
  const int gch = l7 ^ (l8 & 7);
  const int tm = blockIdx.x * 64, tn = blockIdx.y * 128;
  const int wr = w >> 1, wc = w & 1;   // wave = 32x64 quadrant
  const int sl7 = lr & 7;

  const f32x4 zv = {0.f, 0.f, 0.f, 0.f};
  f32x4 acc[2][4];
  #pragma unroll
  for (int mi = 0; mi < 2; mi++)
    #pragma unroll
    for (int ni = 0; ni < 4; ni++) acc[mi][ni] = zv;

  for (int ks = 0; ks < K; ks += 64) {
    #pragma unroll
    for (int ci = 0; ci < 2; ci++) {          // A: 8 chunks
      int c = w + ci * 4;
      async16(A + (size_t)(tm + c * 8 + l8) * K + ks + gch * 8, (void*)(As + c * 512));
    }
    #pragma unroll
    for (int ci = 0; ci < 4; ci++) {          // B: 16 chunks
      int c = w + ci * 4;
      async16(B + (size_t)(tn + c * 8 + l8) * K + ks + gch * 8, (void*)(Bs + c * 512));
    }
    __syncthreads();
    #pragma unroll
    for (int kk = 0; kk < 2; kk++) {
      const int sl = ((kk * 4 + lg) ^ sl7) << 4;
      half8 af[2], bf[4];
      #pragma unroll
      for (int mi = 0; mi < 2; mi++)
        af[mi] = *(const half8*)((const char*)As + (wr * 32 + mi * 16 + lr) * 128 + sl);
      #pragma unroll
      for (int ni = 0; ni < 4; ni++)
        bf[ni] = *(const half8*)((const char*)Bs + (wc * 64 + ni * 16 + lr) * 128 + sl);
      #pragma unroll
      for (int mi = 0; mi < 2; mi++)
        #pragma unroll
        for (int ni = 0; ni < 4; ni++)
          acc[mi][ni] = MFMA_F16(af[mi], bf[ni], acc[mi][ni]);
    }
    __syncthreads();
  }
  #pragma unroll
  for (int mi = 0; mi < 2; mi++) {
    const int row = tm + wr * 32 + mi * 16 + 4 * lg;
    #pragma unroll
    for (int ni = 0; ni < 4; ni++) {
      const int col = tn + wc * 64 + ni * 16 + lr;
      #pragma unroll
      for (int j = 0; j < 4; j++)
        Cf[(size_t)(row + j) * N + col] = acc[mi][ni][j] + bias[col];
    }
  }
}

// -------- Flash attention, swapped-operand form, 64 Q-rows per block -------
// Grid 1024 blocks (4/CU). S^T = mfma(K, Q): lane owns q-col = lane&15 and a
// 16-value kv slice -> softmax is in-lane. Row-sum computed by MFMA with an
// all-ones B-frag (sacc) -> no sum tree, no sum shfls, no epilogue bperm.
// Defer-max check uses per-lane max only (__all covers every lane's slice);
// global-max shfls run only in the rare rescale branch.
__global__ __launch_bounds__(256, 4)
void attn_kernel(const _Float16* __restrict__ Q, const _Float16* __restrict__ Kg,
                 const _Float16* __restrict__ Vg2, _Float16* __restrict__ Og)
{
  __shared__ _Float16 Ks[2][64 * 64];
  __shared__ _Float16 Vt[2][64 * 64];
  const int tid = threadIdx.x;
  const int w = tid >> 6, lane = tid & 63;
  const int lr = lane & 15, lg = lane >> 4;
  const int l8 = lane >> 3, l7 = lane & 7;
  // bijective XCD swizzle: 1024 blocks, 128 per XCD => 4 heads per XCD L2
  const int id = blockIdx.x + 32 * blockIdx.y;
  const int wid = (id & 7) * 128 + (id >> 3);
  const int qb = wid & 31, nb = wid >> 5;
  const size_t hb  = (size_t)(nb >> 4) * SQ * E + (size_t)(nb & 15) * 64;
  const size_t hb2 = (size_t)nb * 64 * SQ;
  const int qbase = qb * 64 + w * 16;
  const int gsl = (l7 ^ (l8 & 7)) * 8;    // pre-swizzled global slot (elems)
  const int sl7 = lr & 7;

  // Q B-frags in registers (already scaled by QSCALE in the projection GEMM)
  half8 qf[2];
  #pragma unroll
  for (int kd = 0; kd < 2; kd++)
    qf[kd] = *(const half8*)(Q + hb + (size_t)(qbase + lr) * E + kd * 32 + lg * 8);

  const f32x4 zv = {0.f, 0.f, 0.f, 0.f};
  f32x4 o[4];
  f32x4 sacc = zv;                      // row-sums via ones-MFMA
  float ms = -1e30f;
  #pragma unroll
  for (int nd = 0; nd < 4; nd++) o[nd] = zv;
  const half8 vones = {(_Float16)1.f, (_Float16)1.f, (_Float16)1.f, (_Float16)1.f,
                       (_Float16)1.f, (_Float16)1.f, (_Float16)1.f, (_Float16)1.f};

  // prologue: stage tile 0 into buffer 0
  #pragma unroll
  for (int ci = 0; ci < 2; ci++) {
    int c = w + ci * 4;
    async16(Kg  + hb  + (size_t)(c * 8 + l8) * E  + gsl, (void*)(Ks[0] + c * 512));
    async16(Vg2 + hb2 + (size_t)(c * 8 + l8) * SQ + gsl, (void*)(Vt[0] + c * 512));
  }
  __syncthreads();

  int cur = 0;
  for (int t = 0; t < 32; t++) {
    if (t < 31) {     // issue next-tile staging early
      const int kvb = (t + 1) * 64;
      #pragma unroll
      for (int ci = 0; ci < 2; ci++) {
        int c = w + ci * 4;
        async16(Kg  + hb  + (size_t)(kvb + c * 8 + l8) * E + gsl, (void*)(Ks[cur ^ 1] + c * 512));
        async16(Vg2 + hb2 + (size_t)(c * 8 + l8) * SQ + kvb + gsl, (void*)(Vt[cur ^ 1] + c * 512));
      }
    }
    // S^T = K Q^T (exp2-domain scaled): s[ni] rows kv=16ni+4lg+j, col q=lr
    f32x4 s[4];
    #pragma unroll
    for (int ni = 0; ni < 4; ni++) s[ni] = zv;
    #pragma unroll
    for (int kd = 0; kd < 2; kd++) {
      const int sl = ((kd * 4 + lg) ^ sl7) << 4;
      half8 kf[4];
      #pragma unroll
      for (int ni = 0; ni < 4; ni++)
        kf[ni] = *(const half8*)((const char*)Ks[cur] + (ni * 16 + lr) * 128 + sl);
      #pragma unroll
      for (int ni = 0; ni < 4; ni++)
        s[ni] = MFMA_F16(kf[ni], qf[kd], s[ni]);
    }
    // online softmax (exp2 domain), defer-max with per-lane check
    {
      float m0 = fmaxf(fmaxf(s[0][0], s[0][1]), fmaxf(s[0][2], s[0][3]));
      float m1 = fmaxf(fmaxf(s[1][0], s[1][1]), fmaxf(s[1][2], s[1][3]));
      float m2 = fmaxf(fmaxf(s[2][0], s[2][1]), fmaxf(s[2][2], s[2][3]));
      float m3 = fmaxf(fmaxf(s[3][0], s[3][1]), fmaxf(s[3][2], s[3][3]));
      float mx = fmaxf(fmaxf(m0, m1), fmaxf(m2, m3));   // per-lane (local) max
      if (__all(mx <= ms + 8.0f)) {
        // keep old max; P bounded by 2^8; sums handled by ones-MFMA
        #pragma unroll
        for (int ni = 0; ni < 4; ni++)
          #pragma unroll
          for (int jr = 0; jr < 4; jr++)
            s[ni][jr] = EXP2(s[ni][jr] - ms);
      } else {
        mx = fmaxf(mx, __shfl_xor(mx, 16));
        mx = fmaxf(mx, __shfl_xor(mx, 32));
        float mnew = fmaxf(ms, mx);
        float corr = EXP2(ms - mnew);
        ms = mnew;
        #pragma unroll
        for (int ni = 0; ni < 4; ni++)
          #pragma unroll
          for (int jr = 0; jr < 4; jr++)
            s[ni][jr] = EXP2(s[ni][jr] - ms);
        // rescale O and sacc: corr lives at lane q=lr; rows are q = 4lg+jr
        #pragma unroll
        for (int jr = 0; jr < 4; jr++) {
          float c4 = bperm_f(4 * lg + jr, corr);
          #pragma unroll
          for (int nd = 0; nd < 4; nd++) o[nd][jr] *= c4;
          sacc[jr] *= c4;
        }
      }
    }
    // pack P A-frags in-lane via cvt_pkrtz: k-slot j' at kk -> kv = 32kk+16(j'>>2)+4lg+(j'&3)
    half8 pa[2];
    #pragma unroll
    for (int kk = 0; kk < 2; kk++) {
      union { half8 h8; fp16x2 h2[4]; } u;
      u.h2[0] = __builtin_amdgcn_cvt_pkrtz(s[2 * kk][0], s[2 * kk][1]);
      u.h2[1] = __builtin_amdgcn_cvt_pkrtz(s[2 * kk][2], s[2 * kk][3]);
      u.h2[2] = __builtin_amdgcn_cvt_pkrtz(s[2 * kk + 1][0], s[2 * kk + 1][1]);
      u.h2[3] = __builtin_amdgcn_cvt_pkrtz(s[2 * kk + 1][2], s[2 * kk + 1][3]);
      pa[kk] = u.h8;
    }
    // O += P V ; rowsum += P 1  (B-frags from permuted Vt; ones-frag for sums)
    #pragma unroll
    for (int kk = 0; kk < 2; kk++) {
      const int sl = ((kk * 4 + lg) ^ sl7) << 4;
      half8 vf[4];
      #pragma unroll
      for (int nd = 0; nd < 4; nd++)
        vf[nd] = *(const half8*)((const char*)Vt[cur] + (nd * 16 + lr) * 128 + sl);
      #pragma unroll
      for (int nd = 0; nd < 4; nd++)
        o[nd] = MFMA_F16(pa[kk], vf[nd], o[nd]);
      sacc = MFMA_F16(pa[kk], vones, sacc);
    }
    __syncthreads();
    cur ^= 1;
  }
  // epilogue: O /= rowsum (sacc[jr] is already per-row — no bperm needed)
  #pragma unroll
  for (int jr = 0; jr < 4; jr++) {
    const float lv = 1.0f / sacc[jr];
    const int row = qbase + 4 * lg + jr;
    #pragma unroll
    for (int nd = 0; nd < 4; nd++)
      Og[hb + (size_t)row * E + nd * 16 + lr] = (_Float16)(o[nd][jr] * lv);
  }
}

extern "C" void kernel_launch(void* const* d_in, const int* in_sizes, int n_in,
                              void* d_out, int out_size, void* d_ws, size_t ws_size,
                              hipStream_t stream)
{
  const float* x  = (const float*)d_in[0];
  const float* Wq = (const float*)d_in[1];
  const float* Wk = (const float*)d_in[2];
  const float* Wv = (const float*)d_in[3];
  const float* Wo = (const float*)d_in[4];
  const float* bo = (const float*)d_in[5];
  char* ws = (char*)d_ws;
  const size_t MB = 1024u * 1024u;
  // ws layout (32 MiB): [0,8) xh | [8,16) weights f16 | [16,24) Vg2 | [24,32) Oh
  _Float16* xh  = (_Float16*)(ws);
  _Float16* Wqh = (_Float16*)(ws + 8 * MB);
  _Float16* Wkh = (_Float16*)(ws + 10 * MB);
  _Float16* Wvh = (_Float16*)(ws + 12 * MB);
  _Float16* Woh = (_Float16*)(ws + 14 * MB);
  _Float16* Vg2 = (_Float16*)(ws + 16 * MB);
  _Float16* Oh  = (_Float16*)(ws + 24 * MB);
  // Q and K parked in d_out (dead before final GEMM overwrites it)
  _Float16* Qh  = (_Float16*)(d_out);
  _Float16* Kh  = (_Float16*)((char*)d_out + 8 * MB);
  float* Y = (float*)d_out;

  cvtall<<<8192, 256, 0, stream>>>(x, Wq, Wk, Wv, Wo, xh, Wqh, Wkh, Wvh, Woh);

  gemm_qkv<<<dim3(32, 8, 3), 256, 0, stream>>>(
      xh, Wqh, Wkh, Wvh, Qh, Kh, Vg2, NR, E, E);

  attn_kernel<<<dim3(32, 32), 256, 0, stream>>>(Qh, Kh, Vg2, Oh);

  gemm_o<<<dim3(64, 8), 256, 0, stream>>>(Oh, Woh, Y, bo, NR, E, E);
}